// Round 2
// 242.667 us; speedup vs baseline: 1.0130x; 1.0130x over previous
//
#include <hip/hip_runtime.h>
#include <math.h>

// Problem: B=64, N=4096, K=128. Labels C in [0,128).
// out[b,i,k] = (rank(C[b,i]) == k) ? u : ndtri(clip(U,1e-7,1-1e-7) * Phi(u))
// where u = mu + sigma*eps[b,i], rank = index of C[b,i] in sorted unique(C).
//
// Structure:
//   ws[0..3]  : 128-bit presence bitmap over label values (zeroed via memset)
//   ws+256    : float2 {u, Phi(u)} per row (2 MB)
// Pass 1 (row_kernel): presence bitmap + per-row u/phi  (vectorized 4 rows/thread)
// Pass 2 (map_kernel): one thread per float4 of U; branchless Acklam ndtri
//                      with a single shared rcp; nontemporal output stores.

// Native clang vector type — __builtin_nontemporal_store rejects
// HIP_vector_type<float,4> but accepts ext_vector_type.
typedef float vfloat4 __attribute__((ext_vector_type(4)));

// ---------------------------------------------------------------------------
// Acklam's inverse normal CDF, fp32, branchless. Both rational paths are
// evaluated (every wave is divergent anyway: tail probability ~11%/element
// since Phi(u) is uniform), then num/den/scale are selected and ONE rcp is
// paid instead of two. Per-lane arithmetic is bit-identical to the branched
// version: central x = (q*num)*rcp(den); tail x = (+-1*num)*rcp(den), and
// (+-1)*num is an exact sign flip.
__device__ __forceinline__ float ndtri_fast(float p) {
    const float omp  = 1.0f - p;
    const bool upper = p > 0.5f;
    const float pm   = upper ? omp : p;   // min(p, 1-p)
    const bool tail  = pm < 0.02425f;

    // ---- tail branch values (valid/finite for all lanes: pm in (0, 0.5])
    float qt = sqrtf(-2.0f * __logf(pm));
    float numT = -0.007784894002430293f;
    numT = fmaf(numT, qt, -0.3223964580411365f);
    numT = fmaf(numT, qt, -2.400758277161838f);
    numT = fmaf(numT, qt, -2.549732539343734f);
    numT = fmaf(numT, qt,  4.374664141464968f);
    numT = fmaf(numT, qt,  2.938163982698783f);
    float denT = 0.007784695709041462f;
    denT = fmaf(denT, qt, 0.3224671290700398f);
    denT = fmaf(denT, qt, 2.445134137142996f);
    denT = fmaf(denT, qt, 3.754408661907416f);
    denT = fmaf(denT, qt, 1.0f);

    // ---- central branch values
    float qc = p - 0.5f;
    float r  = qc * qc;
    float numC = -39.69683028665376f;
    numC = fmaf(numC, r,  220.9460984245205f);
    numC = fmaf(numC, r, -275.9285104469687f);
    numC = fmaf(numC, r,  138.3577518672690f);
    numC = fmaf(numC, r,  -30.66479806614716f);
    numC = fmaf(numC, r,    2.506628277459239f);
    float denC = -54.47609879822406f;
    denC = fmaf(denC, r,  161.5858368580409f);
    denC = fmaf(denC, r, -155.6989798598866f);
    denC = fmaf(denC, r,   66.80131188771972f);
    denC = fmaf(denC, r,  -13.28068155288572f);
    denC = fmaf(denC, r,    1.0f);

    // ---- select + single rcp
    float num = tail ? numT : numC;
    float den = tail ? denT : denC;
    float s   = tail ? (upper ? -1.0f : 1.0f) : qc;
    return s * num * __builtin_amdgcn_rcpf(den);
}

__device__ __forceinline__ void set_label_bit(int c, unsigned& m0, unsigned& m1,
                                              unsigned& m2, unsigned& m3) {
    unsigned bit = 1u << (c & 31);
    int w = (c >> 5) & 3;
    if      (w == 0) m0 |= bit;
    else if (w == 1) m1 |= bit;
    else if (w == 2) m2 |= bit;
    else             m3 |= bit;
}

// ---------------------------------------------------------------------------
// Pass 1: presence bitmap + per-row (u, Phi(u)); 4 rows per thread.
__global__ void __launch_bounds__(256) row_kernel(
    const int* __restrict__ C,
    const float* __restrict__ eps,
    const float* __restrict__ mu_p,
    const float* __restrict__ sigma_p,
    unsigned* __restrict__ mask,
    float2* __restrict__ uphi,
    int n)
{
    __shared__ unsigned sm[4];
    if (threadIdx.x < 4) sm[threadIdx.x] = 0u;
    __syncthreads();

    const float sg = sigma_p[0];
    const float mu = mu_p[0];
    const float kInvSqrt2 = 0.7071067811865476f;

    int i = blockIdx.x * blockDim.x + threadIdx.x;
    int base = i << 2;
    unsigned m0 = 0, m1 = 0, m2 = 0, m3 = 0;

    if (base + 3 < n) {
        int4   c = *reinterpret_cast<const int4*>(C + base);
        float4 e = *reinterpret_cast<const float4*>(eps + base);
        float u0 = fmaf(sg, e.x, mu);
        float u1 = fmaf(sg, e.y, mu);
        float u2 = fmaf(sg, e.z, mu);
        float u3 = fmaf(sg, e.w, mu);
        float p0 = 0.5f * erfcf(-u0 * kInvSqrt2);
        float p1 = 0.5f * erfcf(-u1 * kInvSqrt2);
        float p2 = 0.5f * erfcf(-u2 * kInvSqrt2);
        float p3 = 0.5f * erfcf(-u3 * kInvSqrt2);
        float4* op = reinterpret_cast<float4*>(uphi + base);
        op[0] = make_float4(u0, p0, u1, p1);
        op[1] = make_float4(u2, p2, u3, p3);
        set_label_bit(c.x, m0, m1, m2, m3);
        set_label_bit(c.y, m0, m1, m2, m3);
        set_label_bit(c.z, m0, m1, m2, m3);
        set_label_bit(c.w, m0, m1, m2, m3);
    } else if (base < n) {
        for (int j = 0; j < 4 && base + j < n; ++j) {
            int cc = C[base + j];
            float ee = eps[base + j];
            float uu = fmaf(sg, ee, mu);
            float pp = 0.5f * erfcf(-uu * kInvSqrt2);
            uphi[base + j] = make_float2(uu, pp);
            set_label_bit(cc, m0, m1, m2, m3);
        }
    }

    #pragma unroll
    for (int off = 32; off > 0; off >>= 1) {
        m0 |= __shfl_down(m0, off, 64);
        m1 |= __shfl_down(m1, off, 64);
        m2 |= __shfl_down(m2, off, 64);
        m3 |= __shfl_down(m3, off, 64);
    }
    if ((threadIdx.x & 63) == 0) {
        if (m0) atomicOr(&sm[0], m0);
        if (m1) atomicOr(&sm[1], m1);
        if (m2) atomicOr(&sm[2], m2);
        if (m3) atomicOr(&sm[3], m3);
    }
    __syncthreads();
    if (threadIdx.x < 4) {
        unsigned v = sm[threadIdx.x];
        if (v) atomicOr(&mask[threadIdx.x], v);
    }
}

// ---------------------------------------------------------------------------
// Pass 2: one thread per float4 (4 consecutive k of one row)
__global__ void __launch_bounds__(256) map_kernel(
    const int* __restrict__ C,
    const float4* __restrict__ U4,
    const float2* __restrict__ uphi,
    const uint4* __restrict__ mask4,
    float4* __restrict__ out4,
    int total4)
{
    int idx = blockIdx.x * blockDim.x + threadIdx.x;
    if (idx >= total4) return;
    int row = idx >> 5;        // K/4 = 32 float4 per row
    int k0  = (idx & 31) << 2;

    float4 Uv = U4[idx];       // longest-latency load first
    float2 up = uphi[row];
    int c = C[row];
    uint4 w = *mask4;          // same 16B for all threads -> L1 broadcast

    // rank = popcount of presence bits strictly below c
    int cw = c >> 5;
    unsigned below = (1u << (c & 31)) - 1u;
    int rank = __popc(w.x & ((0 < cw) ? 0xFFFFFFFFu : ((0 == cw) ? below : 0u)))
             + __popc(w.y & ((1 < cw) ? 0xFFFFFFFFu : ((1 == cw) ? below : 0u)))
             + __popc(w.z & ((2 < cw) ? 0xFFFFFFFFu : ((2 == cw) ? below : 0u)))
             + __popc(w.w & ((3 < cw) ? 0xFFFFFFFFu : ((3 == cw) ? below : 0u)));

    float u = up.x;
    float phi = up.y;

    const float lo = 1e-7f;
    const float hi = 0.99999988079071045f;  // fp32(1 - 1e-7), matches jnp.clip

    // clamp via v_med3_f32 (single instruction)
    float p0 = __builtin_amdgcn_fmed3f(Uv.x, lo, hi) * phi;
    float p1 = __builtin_amdgcn_fmed3f(Uv.y, lo, hi) * phi;
    float p2 = __builtin_amdgcn_fmed3f(Uv.z, lo, hi) * phi;
    float p3 = __builtin_amdgcn_fmed3f(Uv.w, lo, hi) * phi;

    float z0 = ndtri_fast(p0);
    float z1 = ndtri_fast(p1);
    float z2 = ndtri_fast(p2);
    float z3 = ndtri_fast(p3);

    vfloat4 o;
    o.x = (k0 + 0 == rank) ? u : z0;
    o.y = (k0 + 1 == rank) ? u : z1;
    o.z = (k0 + 2 == rank) ? u : z2;
    o.w = (k0 + 3 == rank) ? u : z3;

    // out is never re-read: stream it past the caches
    __builtin_nontemporal_store(o, reinterpret_cast<vfloat4*>(&out4[idx]));
}

extern "C" void kernel_launch(void* const* d_in, const int* in_sizes, int n_in,
                              void* d_out, int out_size, void* d_ws, size_t ws_size,
                              hipStream_t stream) {
    const int*   C     = (const int*)d_in[0];
    const float* eps   = (const float*)d_in[1];
    const float4* U4   = (const float4*)d_in[2];
    const float* mu    = (const float*)d_in[3];
    const float* sigma = (const float*)d_in[4];
    float4* out4 = (float4*)d_out;

    unsigned* mask = (unsigned*)d_ws;
    float2* uphi = (float2*)((char*)d_ws + 256);

    int n = in_sizes[0];           // B*N = 262144 rows
    int total4 = out_size / 4;     // float4 count (unchanged from verified baseline)

    // ws is re-poisoned to 0xAA before every timed launch — zero the bitmap.
    (void)hipMemsetAsync(d_ws, 0, 4 * sizeof(unsigned), stream);

    int n4 = (n + 3) >> 2;
    int rb = (n4 + 255) / 256;
    row_kernel<<<rb, 256, 0, stream>>>(C, eps, mu, sigma, mask, uphi, n);

    int mb = (total4 + 255) / 256;
    map_kernel<<<mb, 256, 0, stream>>>(C, U4, uphi, (const uint4*)mask, out4, total4);
}

// Round 3
// 241.918 us; speedup vs baseline: 1.0161x; 1.0031x over previous
//
#include <hip/hip_runtime.h>
#include <math.h>

// Problem: B=64, N=4096, K=128. Labels C in [0,128).
// out[b,i,k] = (rank(C[b,i]) == k) ? u : ndtri(clip(U,1e-7,1-1e-7) * Phi(u))
// where u = mu + sigma*eps[b,i], rank = index of C[b,i] in sorted unique(C).
//
// Structure (v3):
//   ws[0..3] : 128-bit presence bitmap over label values (zeroed via tiny memset)
// Pass 1 (bitmap_kernel): presence bitmap only — reads just C (1 MiB, ~3 us)
// Pass 2 (map_kernel): one thread per float4 of U; u/Phi(u) recomputed in-place
//   (bit-identical expressions; erfcf redundancy across the row's 32 threads is
//   hidden under the 2 KB/wave HBM traffic); branchless Acklam ndtri with a
//   single rcp; nontemporal output stores.
// The old uphi round-trip (2 MB write + 2 MB read + serial erfcf pass) is gone.

// Native clang vector type — __builtin_nontemporal_store rejects
// HIP_vector_type<float,4> but accepts ext_vector_type.
typedef float vfloat4 __attribute__((ext_vector_type(4)));

// ---------------------------------------------------------------------------
// Acklam's inverse normal CDF, fp32, branchless. Both rational paths are
// evaluated (every wave is divergent anyway: tail probability ~11%/element),
// then num/den/scale are selected and ONE rcp is paid instead of two.
// Per-lane arithmetic is bit-identical to the branched version.
__device__ __forceinline__ float ndtri_fast(float p) {
    const float omp  = 1.0f - p;
    const bool upper = p > 0.5f;
    const float pm   = upper ? omp : p;   // min(p, 1-p)
    const bool tail  = pm < 0.02425f;

    // ---- tail branch values (valid/finite for all lanes: pm in (0, 0.5])
    float qt = sqrtf(-2.0f * __logf(pm));
    float numT = -0.007784894002430293f;
    numT = fmaf(numT, qt, -0.3223964580411365f);
    numT = fmaf(numT, qt, -2.400758277161838f);
    numT = fmaf(numT, qt, -2.549732539343734f);
    numT = fmaf(numT, qt,  4.374664141464968f);
    numT = fmaf(numT, qt,  2.938163982698783f);
    float denT = 0.007784695709041462f;
    denT = fmaf(denT, qt, 0.3224671290700398f);
    denT = fmaf(denT, qt, 2.445134137142996f);
    denT = fmaf(denT, qt, 3.754408661907416f);
    denT = fmaf(denT, qt, 1.0f);

    // ---- central branch values
    float qc = p - 0.5f;
    float r  = qc * qc;
    float numC = -39.69683028665376f;
    numC = fmaf(numC, r,  220.9460984245205f);
    numC = fmaf(numC, r, -275.9285104469687f);
    numC = fmaf(numC, r,  138.3577518672690f);
    numC = fmaf(numC, r,  -30.66479806614716f);
    numC = fmaf(numC, r,    2.506628277459239f);
    float denC = -54.47609879822406f;
    denC = fmaf(denC, r,  161.5858368580409f);
    denC = fmaf(denC, r, -155.6989798598866f);
    denC = fmaf(denC, r,   66.80131188771972f);
    denC = fmaf(denC, r,  -13.28068155288572f);
    denC = fmaf(denC, r,    1.0f);

    // ---- select + single rcp
    float num = tail ? numT : numC;
    float den = tail ? denT : denC;
    float s   = tail ? (upper ? -1.0f : 1.0f) : qc;
    return s * num * __builtin_amdgcn_rcpf(den);
}

__device__ __forceinline__ void set_label_bit(int c, unsigned& m0, unsigned& m1,
                                              unsigned& m2, unsigned& m3) {
    unsigned bit = 1u << (c & 31);
    int w = (c >> 5) & 3;
    if      (w == 0) m0 |= bit;
    else if (w == 1) m1 |= bit;
    else if (w == 2) m2 |= bit;
    else             m3 |= bit;
}

// ---------------------------------------------------------------------------
// Pass 1: presence bitmap only. 4 labels per thread (int4 loads).
__global__ void __launch_bounds__(256) bitmap_kernel(
    const int* __restrict__ C,
    unsigned* __restrict__ mask,
    int n)
{
    __shared__ unsigned sm[4];
    if (threadIdx.x < 4) sm[threadIdx.x] = 0u;
    __syncthreads();

    int i = blockIdx.x * blockDim.x + threadIdx.x;
    int base = i << 2;
    unsigned m0 = 0, m1 = 0, m2 = 0, m3 = 0;

    if (base + 3 < n) {
        int4 c = *reinterpret_cast<const int4*>(C + base);
        set_label_bit(c.x, m0, m1, m2, m3);
        set_label_bit(c.y, m0, m1, m2, m3);
        set_label_bit(c.z, m0, m1, m2, m3);
        set_label_bit(c.w, m0, m1, m2, m3);
    } else {
        for (int j = base; j < n && j < base + 4; ++j)
            set_label_bit(C[j], m0, m1, m2, m3);
    }

    #pragma unroll
    for (int off = 32; off > 0; off >>= 1) {
        m0 |= __shfl_down(m0, off, 64);
        m1 |= __shfl_down(m1, off, 64);
        m2 |= __shfl_down(m2, off, 64);
        m3 |= __shfl_down(m3, off, 64);
    }
    if ((threadIdx.x & 63) == 0) {
        if (m0) atomicOr(&sm[0], m0);
        if (m1) atomicOr(&sm[1], m1);
        if (m2) atomicOr(&sm[2], m2);
        if (m3) atomicOr(&sm[3], m3);
    }
    __syncthreads();
    if (threadIdx.x < 4) {
        unsigned v = sm[threadIdx.x];
        if (v) atomicOr(&mask[threadIdx.x], v);
    }
}

// ---------------------------------------------------------------------------
// Pass 2: one thread per float4 (4 consecutive k of one row).
// u and Phi(u) recomputed here (bit-identical to the old row pass); the 32x
// redundancy per row is pure VALU hidden under HBM traffic.
__global__ void __launch_bounds__(256) map_kernel(
    const int* __restrict__ C,
    const float* __restrict__ eps,
    const float* __restrict__ mu_p,
    const float* __restrict__ sigma_p,
    const float4* __restrict__ U4,
    const uint4* __restrict__ mask4,
    float4* __restrict__ out4,
    int total4)
{
    int idx = blockIdx.x * blockDim.x + threadIdx.x;
    if (idx >= total4) return;
    int row = idx >> 5;        // K/4 = 32 float4 per row
    int k0  = (idx & 31) << 2;

    float4 Uv = U4[idx];       // longest-latency load first
    float  e  = eps[row];      // 32 threads share each value -> L1 broadcast
    int    c  = C[row];
    uint4  w  = *mask4;        // same 16B for all threads -> L1 broadcast

    const float sg = sigma_p[0];   // uniform address -> scalar load
    const float mu = mu_p[0];
    float u   = fmaf(sg, e, mu);
    float phi = 0.5f * erfcf(-u * 0.7071067811865476f);

    // rank = popcount of presence bits strictly below c
    int cw = c >> 5;
    unsigned below = (1u << (c & 31)) - 1u;
    int rank = __popc(w.x & ((0 < cw) ? 0xFFFFFFFFu : ((0 == cw) ? below : 0u)))
             + __popc(w.y & ((1 < cw) ? 0xFFFFFFFFu : ((1 == cw) ? below : 0u)))
             + __popc(w.z & ((2 < cw) ? 0xFFFFFFFFu : ((2 == cw) ? below : 0u)))
             + __popc(w.w & ((3 < cw) ? 0xFFFFFFFFu : ((3 == cw) ? below : 0u)));

    const float lo = 1e-7f;
    const float hi = 0.99999988079071045f;  // fp32(1 - 1e-7), matches jnp.clip

    // clamp via v_med3_f32 (single instruction)
    float p0 = __builtin_amdgcn_fmed3f(Uv.x, lo, hi) * phi;
    float p1 = __builtin_amdgcn_fmed3f(Uv.y, lo, hi) * phi;
    float p2 = __builtin_amdgcn_fmed3f(Uv.z, lo, hi) * phi;
    float p3 = __builtin_amdgcn_fmed3f(Uv.w, lo, hi) * phi;

    float z0 = ndtri_fast(p0);
    float z1 = ndtri_fast(p1);
    float z2 = ndtri_fast(p2);
    float z3 = ndtri_fast(p3);

    vfloat4 o;
    o.x = (k0 + 0 == rank) ? u : z0;
    o.y = (k0 + 1 == rank) ? u : z1;
    o.z = (k0 + 2 == rank) ? u : z2;
    o.w = (k0 + 3 == rank) ? u : z3;

    // out is never re-read: stream it past the caches
    __builtin_nontemporal_store(o, reinterpret_cast<vfloat4*>(&out4[idx]));
}

extern "C" void kernel_launch(void* const* d_in, const int* in_sizes, int n_in,
                              void* d_out, int out_size, void* d_ws, size_t ws_size,
                              hipStream_t stream) {
    const int*   C     = (const int*)d_in[0];
    const float* eps   = (const float*)d_in[1];
    const float4* U4   = (const float4*)d_in[2];
    const float* mu    = (const float*)d_in[3];
    const float* sigma = (const float*)d_in[4];
    float4* out4 = (float4*)d_out;

    unsigned* mask = (unsigned*)d_ws;

    int n = in_sizes[0];           // B*N = 262144 rows
    int total4 = out_size / 4;     // float4 count (unchanged from verified baseline)

    // ws is re-poisoned to 0xAA before every timed launch — zero the bitmap.
    (void)hipMemsetAsync(d_ws, 0, 4 * sizeof(unsigned), stream);

    int n4 = (n + 3) >> 2;
    int bb = (n4 + 255) / 256;
    bitmap_kernel<<<bb, 256, 0, stream>>>(C, mask, n);

    int mb = (total4 + 255) / 256;
    map_kernel<<<mb, 256, 0, stream>>>(C, eps, mu, sigma, U4,
                                       (const uint4*)mask, out4, total4);
}